// Round 6
// baseline (128.564 us; speedup 1.0000x reference)
//
#include <hip/hip_runtime.h>
#include <cstddef>
#include <cstdint>

constexpr int B_ = 64, C_ = 128, T_ = 1024, H_ = 512, ENC_ = 512;
#define ALPHA_F 0.9512294245007140f
#define ONEMA_F 0.0487705754992860f

typedef short v8s __attribute__((ext_vector_type(8)));
typedef float v4f __attribute__((ext_vector_type(4)));

#define GL16(gp, lp) __builtin_amdgcn_global_load_lds( \
    (const __attribute__((address_space(1))) unsigned int*)(gp), \
    (__attribute__((address_space(3))) unsigned int*)(lp), 16, 0, 0)

__device__ __forceinline__ unsigned short f2bf(float f) {
    union { float f; unsigned u; } v; v.f = f;
    unsigned r = v.u + 0x7FFFu + ((v.u >> 16) & 1u);
    return (unsigned short)(r >> 16);
}
__device__ __forceinline__ float bf2f(unsigned short h) {
    union { unsigned u; float f; } v; v.u = ((unsigned)h) << 16;
    return v.f;
}

// ---------------------------------------------------------------------------
// cast w1 (fp32) -> bf16
// ---------------------------------------------------------------------------
__global__ __launch_bounds__(256) void k_cast(
    const float* __restrict__ in, unsigned short* __restrict__ out, int n4)
{
    int i = blockIdx.x * 256 + threadIdx.x;
    if (i < n4) {
        float4 v = ((const float4*)in)[i];
        ushort4 h;
        h.x = f2bf(v.x); h.y = f2bf(v.y); h.z = f2bf(v.z); h.w = f2bf(v.w);
        ((ushort4*)out)[i] = h;
    }
}

// ---------------------------------------------------------------------------
// W_eff = (I + gate) @ w2 -> bf16,  b_eff = (I + gate) @ b2 -> fp32
// ---------------------------------------------------------------------------
__global__ __launch_bounds__(128) void k_weff(
    const float* __restrict__ w2, const float* __restrict__ b2,
    const float* __restrict__ og, unsigned short* __restrict__ Weffb,
    float* __restrict__ beff)
{
    const int c = blockIdx.x;
    const int tid = threadIdx.x;
    __shared__ float ogs[C_];
    float g = og[c * C_ + tid];
    if (tid == c) g = 0.f;
    ogs[tid] = g;
    __syncthreads();

    float acc[4];
#pragma unroll
    for (int s = 0; s < 4; ++s) acc[s] = w2[c * H_ + tid + s * 128];
    for (int cp = 0; cp < C_; ++cp) {
        const float w = ogs[cp];
#pragma unroll
        for (int s = 0; s < 4; ++s) acc[s] += w * w2[cp * H_ + tid + s * 128];
    }
#pragma unroll
    for (int s = 0; s < 4; ++s) Weffb[c * H_ + tid + s * 128] = f2bf(acc[s]);

    if (tid == 0) {
        float a = b2[c];
        for (int cp = 0; cp < C_; ++cp) a += ogs[cp] * b2[cp];
        beff[c] = a;
    }
}

// ---------------------------------------------------------------------------
// depthwise conv (K=5, same-pad) -> enc bf16 [B*T][ENC]
// ---------------------------------------------------------------------------
__global__ __launch_bounds__(256) void k_conv(
    const float* __restrict__ x, const float* __restrict__ cw,
    const float* __restrict__ cb, unsigned short* __restrict__ enc)
{
    const int bid = blockIdx.x;
    const int b  = bid >> 5;
    const int t0 = ((bid >> 2) & 7) << 7;
    const int c0 = (bid & 3) << 5;
    const int tid = threadIdx.x;
    const int c_l = tid & 31;
    const int tl0 = tid >> 5;

    __shared__ float xs[132][33];

    const int c = c0 + c_l;
    float wreg[20];
    {
        const float4* wp = (const float4*)(cw + (size_t)c * 20);
#pragma unroll
        for (int q = 0; q < 5; ++q) {
            const float4 v = wp[q];
            wreg[q * 4 + 0] = v.x; wreg[q * 4 + 1] = v.y;
            wreg[q * 4 + 2] = v.z; wreg[q * 4 + 3] = v.w;
        }
    }
    const float4 breg = *(const float4*)(cb + (size_t)c * 4);

    const float* xrow = x + ((size_t)b * C_ + c0) * T_;
    for (int i = tid; i < 32 * 132; i += 256) {
        const int cc = i / 132;
        const int j  = i - cc * 132;
        const int t  = t0 - 2 + j;
        float v = 0.f;
        if (t >= 0 && t < T_) v = xrow[(size_t)cc * T_ + t];
        xs[j][cc] = v;
    }
    __syncthreads();

    unsigned short* erow = enc + (size_t)(b * T_ + t0) * 512 + c * 4;
#pragma unroll
    for (int tt = 0; tt < 16; ++tt) {
        const int tl = tl0 + (tt << 3);
        const float x0 = xs[tl][c_l],     x1 = xs[tl + 1][c_l],
                    x2 = xs[tl + 2][c_l], x3 = xs[tl + 3][c_l],
                    x4 = xs[tl + 4][c_l];
        ushort4 hv;
        {
            const float a0 = breg.x + wreg[0]*x0 + wreg[1]*x1 + wreg[2]*x2 + wreg[3]*x3 + wreg[4]*x4;
            const float a1 = breg.y + wreg[5]*x0 + wreg[6]*x1 + wreg[7]*x2 + wreg[8]*x3 + wreg[9]*x4;
            const float a2 = breg.z + wreg[10]*x0 + wreg[11]*x1 + wreg[12]*x2 + wreg[13]*x3 + wreg[14]*x4;
            const float a3 = breg.w + wreg[15]*x0 + wreg[16]*x1 + wreg[17]*x2 + wreg[18]*x3 + wreg[19]*x4;
            hv.x = f2bf(a0); hv.y = f2bf(a1); hv.z = f2bf(a2); hv.w = f2bf(a3);
        }
        *(ushort4*)(erow + (size_t)tl * 512) = hv;
    }
}

// ---------------------------------------------------------------------------
// GEMM1, 8-phase 256x256 (T2+T3+T4+T5), BK=64, 8 waves. Unchanged from r5.
// ---------------------------------------------------------------------------
__global__ __launch_bounds__(512, 2) void k_gemm1_8p(
    const unsigned short* __restrict__ A, const unsigned short* __restrict__ Bw,
    const float* __restrict__ bias, unsigned short* __restrict__ out)
{
    __shared__ unsigned char lds[131072];
    const int tid = threadIdx.x;
    const int lane = tid & 63;
    const int w = tid >> 6;
    const int wr = w >> 2;
    const int wc = w & 3;
    const int l15 = lane & 15;
    const int klo = lane >> 4;

    const int d = blockIdx.x;
    const int g = ((d & 7) << 6) + (d >> 3);
    const int m0 = (g >> 1) << 8;
    const int n0 = (g & 1) << 8;

    const int srow = tid >> 3;
    const int scol = ((tid & 7) ^ (srow & 7)) << 4;

    const unsigned char* Ag = (const unsigned char*)A;
    const unsigned char* Bg = (const unsigned char*)Bw;

    v4f acc[8][4];
#pragma unroll
    for (int i = 0; i < 8; ++i)
#pragma unroll
        for (int j = 0; j < 4; ++j) acc[i][j] = (v4f)0.f;

    v8s pa[2][2], pb[4][2];

#define STAGE(bufb, isB, h, ktv) do { \
    const unsigned char* sg_ = ((isB) ? Bg : Ag) + \
        (size_t)(((isB) ? n0 : m0) + (h)*128 + srow) * 1024 + (ktv)*128 + scol; \
    unsigned char* sl_ = lds + (bufb)*65536 + (isB)*32768 + (h)*16384 + tid*16; \
    GL16(sg_, sl_); \
    GL16(sg_ + 65536, sl_ + 8192); \
} while(0)

#define LDA8(bufb, q) do { \
    _Pragma("unroll") \
    for (int mi2_ = 0; mi2_ < 2; ++mi2_) { \
      _Pragma("unroll") \
      for (int ks_ = 0; ks_ < 2; ++ks_) { \
        const int row_ = wr*128 + ((q)*2 + mi2_)*16 + l15; \
        pa[mi2_][ks_] = *(const v8s*)(lds + (bufb)*65536 + row_*128 + \
            ((ks_*64 + klo*16) ^ ((row_ & 7) << 4))); \
      } } \
} while(0)

#define LDB8(bufb) do { \
    _Pragma("unroll") \
    for (int ni_ = 0; ni_ < 4; ++ni_) { \
      _Pragma("unroll") \
      for (int ks_ = 0; ks_ < 2; ++ks_) { \
        const int n_ = wc*64 + ni_*16 + l15; \
        pb[ni_][ks_] = *(const v8s*)(lds + (bufb)*65536 + 32768 + n_*128 + \
            ((ks_*64 + klo*16) ^ ((n_ & 7) << 4))); \
      } } \
} while(0)

#define MM8(q) do { \
    __builtin_amdgcn_s_setprio(1); \
    _Pragma("unroll") \
    for (int mi2_ = 0; mi2_ < 2; ++mi2_) \
      _Pragma("unroll") \
      for (int ni_ = 0; ni_ < 4; ++ni_) \
        _Pragma("unroll") \
        for (int ks_ = 0; ks_ < 2; ++ks_) \
          acc[(q)*2+mi2_][ni_] = __builtin_amdgcn_mfma_f32_16x16x32_bf16( \
              pa[mi2_][ks_], pb[ni_][ks_], acc[(q)*2+mi2_][ni_], 0, 0, 0); \
    __builtin_amdgcn_s_setprio(0); \
} while(0)

#define BAR8() do { __builtin_amdgcn_sched_barrier(0); \
    __builtin_amdgcn_s_barrier(); \
    __builtin_amdgcn_sched_barrier(0); } while(0)
#define WVM(n) do { asm volatile("s_waitcnt vmcnt(" #n ")" ::: "memory"); \
    __builtin_amdgcn_sched_barrier(0); } while(0)

    STAGE(0,1,0,0); STAGE(0,1,1,0);
    STAGE(0,0,0,0); STAGE(0,0,1,0);
    STAGE(1,1,0,1); STAGE(1,1,1,1);
    WVM(4); BAR8();

    for (int j = 0; j < 4; ++j) {
        const int sA  = 2*j + 1;
        const int sB0 = (2*j + 2) & 7;
        const int sB1 = (2*j + 3) & 7;
        LDA8(0,0); LDB8(0); STAGE(1,0,0,sA);  BAR8(); MM8(0); BAR8();
        LDA8(0,1);          STAGE(1,0,1,sA);  BAR8(); MM8(1); BAR8();
        LDA8(0,2);          STAGE(0,1,0,sB0); BAR8(); MM8(2); BAR8();
        LDA8(0,3);          STAGE(0,1,1,sB0); BAR8(); MM8(3); WVM(4); BAR8();
        LDA8(1,0); LDB8(1); STAGE(0,0,0,sB0); BAR8(); MM8(0); BAR8();
        LDA8(1,1);          STAGE(0,0,1,sB0); BAR8(); MM8(1); BAR8();
        LDA8(1,2);          STAGE(1,1,0,sB1); BAR8(); MM8(2); BAR8();
        LDA8(1,3);          STAGE(1,1,1,sB1); BAR8(); MM8(3); WVM(4); BAR8();
    }

    WVM(0); BAR8();

#pragma unroll
    for (int mi = 0; mi < 8; ++mi)
#pragma unroll
        for (int ni = 0; ni < 4; ++ni) {
            const int n = wc*64 + ni*16 + l15;
            const float bi = bias[n0 + n];
#pragma unroll
            for (int r = 0; r < 4; ++r) {
                const int m = wr*128 + mi*16 + klo*4 + r;
                *(unsigned short*)(lds + m*512 + ((2*n) ^ ((m & 7) << 4))) =
                    f2bf(acc[mi][ni][r] + bi);
            }
        }
    BAR8();
#pragma unroll
    for (int it = 0; it < 16; ++it) {
        const int idx = it*512 + tid;
        const int r = idx >> 5, s = idx & 31;
        const int4 v = *(const int4*)(lds + r*512 + ((s*16) ^ ((r & 7) << 4)));
        *(int4*)(&out[(size_t)(m0 + r)*512 + n0 + s*8]) = v;
    }
#undef STAGE
#undef LDA8
#undef LDB8
#undef MM8
}

// ---------------------------------------------------------------------------
// GEMM2 v2: D[m=c(128)][n=(b,t) 128-tile] = Weffb @ mem^T + beff, out fp32.
// Double-buffered BK=64, counted vmcnt(8) (T3-min pipeline), setprio MFMA,
// 64 KB LDS -> 2 blocks/CU. fp32 C staged through LDS -> coalesced dwordx4.
// ---------------------------------------------------------------------------
__global__ __launch_bounds__(256, 2) void k_mfma1(
    const unsigned short* __restrict__ A, const unsigned short* __restrict__ Bm,
    const float* __restrict__ bias, float* __restrict__ out)
{
    __shared__ unsigned char lds[65536];  // buf*32768 { A 16K | B 16K }; epilogue reuses all
    const int tid = threadIdx.x;
    const int lane = tid & 63;
    const int w = tid >> 6;
    const int wm = (w & 1) << 6, wn = (w >> 1) << 6;
    const int l15 = lane & 15, klo = lane >> 4;

    const int n0 = blockIdx.x << 7;

    const int srow = tid >> 3;                       // 0..31 (+i*32)
    const int scol = ((tid & 7) ^ (srow & 7)) << 4;  // inverse-swizzled source

#define ST1(buf, k0) do { \
    _Pragma("unroll") for (int i_ = 0; i_ < 4; ++i_) { \
        GL16((const unsigned char*)A + (size_t)(srow + i_*32)*1024 + (k0)*2 + scol, \
             lds + (buf)*32768 + i_*4096 + tid*16); \
        GL16((const unsigned char*)Bm + (size_t)(n0 + srow + i_*32)*1024 + (k0)*2 + scol, \
             lds + (buf)*32768 + 16384 + i_*4096 + tid*16); \
    } } while(0)
#define BARX() do { __builtin_amdgcn_sched_barrier(0); \
    __builtin_amdgcn_s_barrier(); \
    __builtin_amdgcn_sched_barrier(0); } while(0)

    v4f acc[4][4];
#pragma unroll
    for (int i = 0; i < 4; ++i)
#pragma unroll
        for (int j = 0; j < 4; ++j) acc[i][j] = (v4f)0.f;

    ST1(0, 0);
    for (int kt = 0; kt < 8; ++kt) {
        const int cur = kt & 1;
        if (kt < 7) {
            ST1(cur ^ 1, (kt + 1) * 64);
            asm volatile("s_waitcnt vmcnt(8)" ::: "memory");
        } else {
            asm volatile("s_waitcnt vmcnt(0)" ::: "memory");
        }
        __builtin_amdgcn_sched_barrier(0);
        __builtin_amdgcn_s_barrier();
        __builtin_amdgcn_sched_barrier(0);

        const unsigned char* base = lds + cur * 32768;
#pragma unroll
        for (int ks = 0; ks < 2; ++ks) {
            v8s af[4], bfr[4];
#pragma unroll
            for (int i = 0; i < 4; ++i) {
                const int ra = wm + i * 16 + l15;
                const int rb = wn + i * 16 + l15;
                const int kb = ks * 64 + klo * 16;
                af[i]  = *(const v8s*)(base + ra * 128 + (kb ^ ((ra & 7) << 4)));
                bfr[i] = *(const v8s*)(base + 16384 + rb * 128 + (kb ^ ((rb & 7) << 4)));
            }
            __builtin_amdgcn_s_setprio(1);
#pragma unroll
            for (int mi = 0; mi < 4; ++mi)
#pragma unroll
                for (int ni = 0; ni < 4; ++ni)
                    acc[mi][ni] = __builtin_amdgcn_mfma_f32_16x16x32_bf16(
                        af[mi], bfr[ni], acc[mi][ni], 0, 0, 0);
            __builtin_amdgcn_s_setprio(0);
        }
        BARX();
    }

    // epilogue: fp32 C tile (128x128 = 64 KB) via LDS, coalesced stores
#pragma unroll
    for (int mi = 0; mi < 4; ++mi)
#pragma unroll
        for (int ni = 0; ni < 4; ++ni) {
            const int n = wn + ni * 16 + l15;
#pragma unroll
            for (int r = 0; r < 4; ++r) {
                const int m = wm + mi * 16 + klo * 4 + r;
                *(float*)(lds + m * 512 + ((n * 4) ^ (((m >> 2) & 3) << 5))) =
                    acc[mi][ni][r] + bias[m];
            }
        }
    BARX();
    const int b = n0 >> 10, t0 = n0 & 1023;
#pragma unroll
    for (int it = 0; it < 16; ++it) {
        const int idx = it * 256 + tid;
        const int r = idx >> 5, s = idx & 31;
        const int4 v = *(const int4*)(lds + r * 512 + ((s * 16) ^ (((r >> 2) & 3) << 5)));
        *(int4*)(&out[((size_t)(b * C_ + r) << 10) + t0 + s * 4]) = v;
    }
#undef ST1
#undef BARX
}

// ---------------------------------------------------------------------------
// LIF recurrence v2: 8-way t-split (warmup 128, alpha^128 ~ 1.7e-3), 512
// blocks x 128 threads, uint2 (8 B) loads/stores -> 512 B/wave segments.
// Reads immutable hid (bf16), writes mem into memb (dead enc slot).
// ---------------------------------------------------------------------------
__global__ __launch_bounds__(128) void k_recur(
    const unsigned int* __restrict__ hid, unsigned int* __restrict__ memb)
{
    const int b = blockIdx.x >> 3;
    const int chunk = blockIdx.x & 7;
    const uint2* pin = (const uint2*)(hid + (size_t)b * 262144) + threadIdx.x;
    uint2* pout = (uint2*)(memb + (size_t)b * 262144) + threadIdx.x;
    float m0 = 0.f, m1 = 0.f, m2 = 0.f, m3 = 0.f;
    const int t0 = chunk << 7;

    if (chunk > 0) {  // warmup: read-only, mem assumed 0 at t0-128
        for (int t = t0 - 128; t < t0; t += 16) {
            uint2 v[16];
#pragma unroll
            for (int i = 0; i < 16; ++i) v[i] = pin[(size_t)(t + i) << 7];
#pragma unroll
            for (int i = 0; i < 16; ++i) {
                m0 = ALPHA_F * m0 + ONEMA_F * bf2f((unsigned short)(v[i].x & 0xFFFFu));
                m0 = (m0 >= 1.0f) ? 0.f : m0;
                m1 = ALPHA_F * m1 + ONEMA_F * bf2f((unsigned short)(v[i].x >> 16));
                m1 = (m1 >= 1.0f) ? 0.f : m1;
                m2 = ALPHA_F * m2 + ONEMA_F * bf2f((unsigned short)(v[i].y & 0xFFFFu));
                m2 = (m2 >= 1.0f) ? 0.f : m2;
                m3 = ALPHA_F * m3 + ONEMA_F * bf2f((unsigned short)(v[i].y >> 16));
                m3 = (m3 >= 1.0f) ? 0.f : m3;
            }
        }
    }
    for (int t = t0; t < t0 + 128; t += 16) {
        uint2 v[16];
#pragma unroll
        for (int i = 0; i < 16; ++i) v[i] = pin[(size_t)(t + i) << 7];
#pragma unroll
        for (int i = 0; i < 16; ++i) {
            m0 = ALPHA_F * m0 + ONEMA_F * bf2f((unsigned short)(v[i].x & 0xFFFFu));
            m0 = (m0 >= 1.0f) ? 0.f : m0;
            m1 = ALPHA_F * m1 + ONEMA_F * bf2f((unsigned short)(v[i].x >> 16));
            m1 = (m1 >= 1.0f) ? 0.f : m1;
            m2 = ALPHA_F * m2 + ONEMA_F * bf2f((unsigned short)(v[i].y & 0xFFFFu));
            m2 = (m2 >= 1.0f) ? 0.f : m2;
            m3 = ALPHA_F * m3 + ONEMA_F * bf2f((unsigned short)(v[i].y >> 16));
            m3 = (m3 >= 1.0f) ? 0.f : m3;
            v[i].x = (unsigned)f2bf(m0) | ((unsigned)f2bf(m1) << 16);
            v[i].y = (unsigned)f2bf(m2) | ((unsigned)f2bf(m3) << 16);
        }
#pragma unroll
        for (int i = 0; i < 16; ++i) pout[(size_t)(t + i) << 7] = v[i];
    }
}

// ---------------------------------------------------------------------------
extern "C" void kernel_launch(void* const* d_in, const int* in_sizes, int n_in,
                              void* d_out, int out_size, void* d_ws, size_t ws_size,
                              hipStream_t stream)
{
    const float* x   = (const float*)d_in[0];
    const float* cw  = (const float*)d_in[1];
    const float* cb  = (const float*)d_in[2];
    const float* w1  = (const float*)d_in[3];
    const float* b1  = (const float*)d_in[4];
    const float* w2  = (const float*)d_in[5];
    const float* b2  = (const float*)d_in[6];
    const float* og  = (const float*)d_in[7];

    char* ws = (char*)d_ws;
    unsigned short* enc   = (unsigned short*)ws;               // 64 MiB (later: memb)
    unsigned short* hid   = (unsigned short*)(ws + 67108864);  // 64 MiB
    unsigned short* Weffb = (unsigned short*)(ws + 134217728); // 128 KiB
    float*          beff  = (float*)(ws + 134479872);          // 512 B
    unsigned short* w1b   = (unsigned short*)d_out;            // temp, dead before k_mfma1

    k_cast<<<256, 256, 0, stream>>>(w1, w1b, 65536);
    k_conv<<<2048, 256, 0, stream>>>(x, cw, cb, enc);
    k_weff<<<128, 128, 0, stream>>>(w2, b2, og, Weffb, beff);

    k_gemm1_8p<<<512, 512, 0, stream>>>(enc, w1b, b1, hid);
    k_recur<<<512, 128, 0, stream>>>((const unsigned int*)hid, (unsigned int*)enc);
    k_mfma1<<<512, 256, 0, stream>>>(Weffb, enc, beff, (float*)d_out);
}

// Round 7
// 117.599 us; speedup vs baseline: 1.0932x; 1.0932x over previous
//
#include <hip/hip_runtime.h>
#include <cstddef>
#include <cstdint>

constexpr int B_ = 64, C_ = 128, T_ = 1024, H_ = 512, ENC_ = 512;
#define ALPHA_F 0.9512294245007140f
#define ONEMA_F 0.0487705754992860f

typedef short v8s __attribute__((ext_vector_type(8)));
typedef float v4f __attribute__((ext_vector_type(4)));

#define GL16(gp, lp) __builtin_amdgcn_global_load_lds( \
    (const __attribute__((address_space(1))) unsigned int*)(gp), \
    (__attribute__((address_space(3))) unsigned int*)(lp), 16, 0, 0)

__device__ __forceinline__ unsigned short f2bf(float f) {
    union { float f; unsigned u; } v; v.f = f;
    unsigned r = v.u + 0x7FFFu + ((v.u >> 16) & 1u);
    return (unsigned short)(r >> 16);
}
__device__ __forceinline__ float bf2f(unsigned short h) {
    union { unsigned u; float f; } v; v.u = ((unsigned)h) << 16;
    return v.f;
}

// ---------------------------------------------------------------------------
// k_prep: fused {depthwise conv -> enc bf16} + {cast w1 -> bf16} + {W_eff}.
// grid: [0,2048) conv | [2048,2304) cast | [2304,2432) weff. 256 threads.
// ---------------------------------------------------------------------------
__global__ __launch_bounds__(256) void k_prep(
    const float* __restrict__ x, const float* __restrict__ cw,
    const float* __restrict__ cb, const float* __restrict__ w1,
    const float* __restrict__ w2, const float* __restrict__ b2,
    const float* __restrict__ og, unsigned short* __restrict__ enc,
    unsigned short* __restrict__ w1b, unsigned short* __restrict__ Weffb,
    float* __restrict__ beff)
{
    __shared__ float smem[132 * 33];
    const int bid = blockIdx.x;
    const int tid = threadIdx.x;

    if (bid < 2048) {
        // ---- depthwise conv ----
        const int b  = bid >> 5;
        const int t0 = ((bid >> 2) & 7) << 7;
        const int c0 = (bid & 3) << 5;
        const int c_l = tid & 31;
        const int tl0 = tid >> 5;
        float (*xs)[33] = (float(*)[33])smem;

        const int c = c0 + c_l;
        float wreg[20];
        {
            const float4* wp = (const float4*)(cw + (size_t)c * 20);
#pragma unroll
            for (int q = 0; q < 5; ++q) {
                const float4 v = wp[q];
                wreg[q * 4 + 0] = v.x; wreg[q * 4 + 1] = v.y;
                wreg[q * 4 + 2] = v.z; wreg[q * 4 + 3] = v.w;
            }
        }
        const float4 breg = *(const float4*)(cb + (size_t)c * 4);

        const float* xrow = x + ((size_t)b * C_ + c0) * T_;
        for (int i = tid; i < 32 * 132; i += 256) {
            const int cc = i / 132;
            const int j  = i - cc * 132;
            const int t  = t0 - 2 + j;
            float v = 0.f;
            if (t >= 0 && t < T_) v = xrow[(size_t)cc * T_ + t];
            xs[j][cc] = v;
        }
        __syncthreads();

        unsigned short* erow = enc + (size_t)(b * T_ + t0) * 512 + c * 4;
#pragma unroll
        for (int tt = 0; tt < 16; ++tt) {
            const int tl = tl0 + (tt << 3);
            const float x0 = xs[tl][c_l],     x1 = xs[tl + 1][c_l],
                        x2 = xs[tl + 2][c_l], x3 = xs[tl + 3][c_l],
                        x4 = xs[tl + 4][c_l];
            ushort4 hv;
            const float a0 = breg.x + wreg[0]*x0 + wreg[1]*x1 + wreg[2]*x2 + wreg[3]*x3 + wreg[4]*x4;
            const float a1 = breg.y + wreg[5]*x0 + wreg[6]*x1 + wreg[7]*x2 + wreg[8]*x3 + wreg[9]*x4;
            const float a2 = breg.z + wreg[10]*x0 + wreg[11]*x1 + wreg[12]*x2 + wreg[13]*x3 + wreg[14]*x4;
            const float a3 = breg.w + wreg[15]*x0 + wreg[16]*x1 + wreg[17]*x2 + wreg[18]*x3 + wreg[19]*x4;
            hv.x = f2bf(a0); hv.y = f2bf(a1); hv.z = f2bf(a2); hv.w = f2bf(a3);
            *(ushort4*)(erow + (size_t)tl * 512) = hv;
        }
    } else if (bid < 2304) {
        // ---- cast w1 -> bf16 ----
        const int i = (bid - 2048) * 256 + tid;
        float4 v = ((const float4*)w1)[i];
        ushort4 h;
        h.x = f2bf(v.x); h.y = f2bf(v.y); h.z = f2bf(v.z); h.w = f2bf(v.w);
        ((ushort4*)w1b)[i] = h;
    } else {
        // ---- W_eff = (I+gate) @ w2 -> bf16, b_eff ----
        const int c = bid - 2304;
        float* ogs = smem;
        if (tid < 128) {
            float g = og[c * C_ + tid];
            if (tid == c) g = 0.f;
            ogs[tid] = g;
        }
        __syncthreads();
        if (tid < 128) {
            float acc[4];
#pragma unroll
            for (int s = 0; s < 4; ++s) acc[s] = w2[c * H_ + tid + s * 128];
            for (int cp = 0; cp < C_; ++cp) {
                const float w = ogs[cp];
#pragma unroll
                for (int s = 0; s < 4; ++s) acc[s] += w * w2[cp * H_ + tid + s * 128];
            }
#pragma unroll
            for (int s = 0; s < 4; ++s) Weffb[c * H_ + tid + s * 128] = f2bf(acc[s]);
            if (tid == 0) {
                float a = b2[c];
                for (int cp = 0; cp < C_; ++cp) a += ogs[cp] * b2[cp];
                beff[c] = a;
            }
        }
    }
}

// ---------------------------------------------------------------------------
// GEMM1 wide-N: block = 128 m x 512 n (full N), BK=64, 8 waves (1M x 8N).
// LDS 160 KB: A dbuf 2x16 KB | B dbuf 2x64 KB. One counted WVM(10) + 2
// barriers per K-step; 1-deep prefetch distance ~2400 cyc >> LLC latency.
// B (512 KB) is L2-resident per XCD. Stage uses global_load_lds with
// pre-swizzled SOURCE (rule 21), reads XOR-swizzled, epilogue LDS-staged.
// ---------------------------------------------------------------------------
__global__ __launch_bounds__(512, 2) void k_gemm1w(
    const unsigned short* __restrict__ A, const unsigned short* __restrict__ Bw,
    const float* __restrict__ bias, unsigned short* __restrict__ out)
{
    __shared__ unsigned char lds[163840];  // A0[0,16K) A1[16K,32K) B0[32K,96K) B1[96K,160K)
    const int tid = threadIdx.x;
    const int lane = tid & 63;
    const int w = tid >> 6;          // 0..7 -> n-range w*64
    const int l15 = lane & 15;
    const int klo = lane >> 4;       // 0..3
    const int m0 = blockIdx.x << 7;  // 512 blocks

    const int srow = tid >> 3;                        // 0..63
    const int scol = ((tid & 7) ^ (srow & 7)) << 4;   // inverse-swizzled slot

    const unsigned char* Ag = (const unsigned char*)A;
    const unsigned char* Bg = (const unsigned char*)Bw;

    v4f acc[8][4];
#pragma unroll
    for (int i = 0; i < 8; ++i)
#pragma unroll
        for (int j = 0; j < 4; ++j) acc[i][j] = (v4f)0.f;

#define STG(buf, kt) do { \
    _Pragma("unroll") \
    for (int i_ = 0; i_ < 2; ++i_) \
        GL16(Ag + (size_t)(m0 + i_*64 + srow) * 1024 + (kt)*128 + scol, \
             lds + (buf)*16384 + i_*8192 + tid*16); \
    _Pragma("unroll") \
    for (int i_ = 0; i_ < 8; ++i_) \
        GL16(Bg + (size_t)(i_*64 + srow) * 1024 + (kt)*128 + scol, \
             lds + 32768 + (buf)*65536 + i_*8192 + tid*16); \
} while(0)
#define BARX() do { __builtin_amdgcn_sched_barrier(0); \
    __builtin_amdgcn_s_barrier(); \
    __builtin_amdgcn_sched_barrier(0); } while(0)

    STG(0, 0);
    for (int kt = 0; kt < 8; ++kt) {
        const int buf = kt & 1;
        if (kt < 7) {
            STG(buf ^ 1, kt + 1);
            asm volatile("s_waitcnt vmcnt(10)" ::: "memory");
        } else {
            asm volatile("s_waitcnt vmcnt(0)" ::: "memory");
        }
        BARX();

        const unsigned char* Ab = lds + buf * 16384;
        const unsigned char* Bb = lds + 32768 + buf * 65536;
#pragma unroll
        for (int ks = 0; ks < 2; ++ks) {
            v8s af[8], bf[4];
#pragma unroll
            for (int mi = 0; mi < 8; ++mi) {
                const int row = mi * 16 + l15;
                af[mi] = *(const v8s*)(Ab + row * 128 +
                         ((ks * 64 + klo * 16) ^ ((row & 7) << 4)));
            }
#pragma unroll
            for (int ni = 0; ni < 4; ++ni) {
                const int row = w * 64 + ni * 16 + l15;
                bf[ni] = *(const v8s*)(Bb + row * 128 +
                         ((ks * 64 + klo * 16) ^ ((row & 7) << 4)));
            }
            __builtin_amdgcn_s_setprio(1);
#pragma unroll
            for (int mi = 0; mi < 8; ++mi)
#pragma unroll
                for (int ni = 0; ni < 4; ++ni)
                    acc[mi][ni] = __builtin_amdgcn_mfma_f32_16x16x32_bf16(
                        af[mi], bf[ni], acc[mi][ni], 0, 0, 0);
            __builtin_amdgcn_s_setprio(0);
        }
        BARX();
    }

    // epilogue: C = 128 x 512 bf16 (128 KB) staged in LDS, coalesced stores
#pragma unroll
    for (int mi = 0; mi < 8; ++mi)
#pragma unroll
        for (int ni = 0; ni < 4; ++ni) {
            const int n = w * 64 + ni * 16 + l15;
            const float bi = bias[n];
#pragma unroll
            for (int r = 0; r < 4; ++r) {
                const int m = mi * 16 + klo * 4 + r;
                *(unsigned short*)(lds + m * 1024 + ((2 * n) ^ ((m & 7) << 4))) =
                    f2bf(acc[mi][ni][r] + bi);
            }
        }
    BARX();
#pragma unroll
    for (int it = 0; it < 16; ++it) {
        const int idx = it * 512 + tid;
        const int r = idx >> 6, s = idx & 63;
        const int4 v = *(const int4*)(lds + r * 1024 + ((s * 16) ^ ((r & 7) << 4)));
        *(int4*)(&out[(size_t)(m0 + r) * 512 + s * 8]) = v;
    }
#undef STG
#undef BARX
}

// ---------------------------------------------------------------------------
// GEMM2 (r5-proven): D[m=c][n=(b,t) 128-tile] = Weffb @ mem^T + beff,
// out fp32 direct in (B,C,T). Single-buffered 2-barrier loop.
// ---------------------------------------------------------------------------
__global__ __launch_bounds__(256) void k_gemm2(
    const unsigned short* __restrict__ A, const unsigned short* __restrict__ Bm,
    const float* __restrict__ bias, float* __restrict__ out)
{
    __shared__ unsigned char lds[32768];
    const int tid = threadIdx.x;
    const int lane = tid & 63;
    const int w = tid >> 6;
    const int wm = (w & 1) << 6, wn = (w >> 1) << 6;

    const int n0 = blockIdx.x << 7;

    const int lrow = lane >> 3;
    const int lcol = ((lane & 7) ^ lrow) << 4;
    const unsigned char* pA = (const unsigned char*)A +
        (size_t)(w * 32 + lrow) * 1024 + lcol;
    const unsigned char* pB = (const unsigned char*)Bm +
        (size_t)(n0 + w * 32 + lrow) * 1024 + lcol;
    unsigned char* lA = lds + w * 4096;
    unsigned char* lB = lds + 16384 + w * 4096;

    v4f acc[4][4];
#pragma unroll
    for (int i = 0; i < 4; ++i)
#pragma unroll
        for (int j = 0; j < 4; ++j) acc[i][j] = (v4f)0.f;

    for (int k0 = 0; k0 < 512; k0 += 64) {
        __syncthreads();
#pragma unroll
        for (int i = 0; i < 4; ++i) {
            GL16(pA + (size_t)i * 8192 + k0 * 2, lA + i * 1024);
            GL16(pB + (size_t)i * 8192 + k0 * 2, lB + i * 1024);
        }
        __syncthreads();
#pragma unroll
        for (int ks = 0; ks < 2; ++ks) {
            v8s af[4], bfr[4];
#pragma unroll
            for (int i = 0; i < 4; ++i) {
                const int ra = wm + i * 16 + (lane & 15);
                const int rb = wn + i * 16 + (lane & 15);
                const int kb = ks * 64 + ((lane >> 4) << 4);
                af[i]  = *(const v8s*)(lds + ra * 128 + (kb ^ ((ra & 7) << 4)));
                bfr[i] = *(const v8s*)(lds + 16384 + rb * 128 + (kb ^ ((rb & 7) << 4)));
            }
#pragma unroll
            for (int mi = 0; mi < 4; ++mi)
#pragma unroll
                for (int ni = 0; ni < 4; ++ni)
                    acc[mi][ni] = __builtin_amdgcn_mfma_f32_16x16x32_bf16(
                        af[mi], bfr[ni], acc[mi][ni], 0, 0, 0);
        }
    }

#pragma unroll
    for (int mi = 0; mi < 4; ++mi)
#pragma unroll
        for (int ni = 0; ni < 4; ++ni) {
            const int n = n0 + wn + ni * 16 + (lane & 15);  // (b,t)
            const int b = n >> 10, t = n & 1023;
#pragma unroll
            for (int r = 0; r < 4; ++r) {
                const int c = wm + mi * 16 + ((lane >> 4) << 2) + r;
                out[((size_t)(b * C_ + c) << 10) + t] = acc[mi][ni][r] + bias[c];
            }
        }
}

// ---------------------------------------------------------------------------
// LIF recurrence (r5-proven): 4-way t-split with 128-step warmup
// (alpha^128 ~ 1.7e-3, |mem| ~ 0.02 << threshold 1 -> error ~3e-4).
// Reads immutable hid (bf16), writes mem into memb (dead enc slot).
// ---------------------------------------------------------------------------
__global__ __launch_bounds__(256) void k_recur(
    const unsigned int* __restrict__ hid, unsigned int* __restrict__ memb)
{
    const int j = blockIdx.x >> 6;
    const int b = blockIdx.x & 63;
    const size_t base = (size_t)b * 262144 + threadIdx.x;
    const unsigned int* pin = hid + base;
    unsigned int* pout = memb + base;
    float ma = 0.f, mb = 0.f;
    const int t0 = j << 8;

    if (j > 0) {
        for (int t = t0 - 128; t < t0; t += 16) {
            unsigned int v[16];
#pragma unroll
            for (int i = 0; i < 16; ++i) v[i] = pin[(size_t)(t + i) << 8];
#pragma unroll
            for (int i = 0; i < 16; ++i) {
                ma = ALPHA_F * ma + ONEMA_F * bf2f((unsigned short)(v[i] & 0xFFFFu));
                ma = (ma >= 1.0f) ? 0.f : ma;
                mb = ALPHA_F * mb + ONEMA_F * bf2f((unsigned short)(v[i] >> 16));
                mb = (mb >= 1.0f) ? 0.f : mb;
            }
        }
    }
    for (int t = t0; t < t0 + 256; t += 16) {
        unsigned int v[16];
#pragma unroll
        for (int i = 0; i < 16; ++i) v[i] = pin[(size_t)(t + i) << 8];
#pragma unroll
        for (int i = 0; i < 16; ++i) {
            ma = ALPHA_F * ma + ONEMA_F * bf2f((unsigned short)(v[i] & 0xFFFFu));
            ma = (ma >= 1.0f) ? 0.f : ma;
            mb = ALPHA_F * mb + ONEMA_F * bf2f((unsigned short)(v[i] >> 16));
            mb = (mb >= 1.0f) ? 0.f : mb;
            v[i] = (unsigned)f2bf(ma) | ((unsigned)f2bf(mb) << 16);
        }
#pragma unroll
        for (int i = 0; i < 16; ++i) pout[(size_t)(t + i) << 8] = v[i];
    }
}

// ---------------------------------------------------------------------------
extern "C" void kernel_launch(void* const* d_in, const int* in_sizes, int n_in,
                              void* d_out, int out_size, void* d_ws, size_t ws_size,
                              hipStream_t stream)
{
    const float* x   = (const float*)d_in[0];
    const float* cw  = (const float*)d_in[1];
    const float* cb  = (const float*)d_in[2];
    const float* w1  = (const float*)d_in[3];
    const float* b1  = (const float*)d_in[4];
    const float* w2  = (const float*)d_in[5];
    const float* b2  = (const float*)d_in[6];
    const float* og  = (const float*)d_in[7];

    char* ws = (char*)d_ws;
    unsigned short* enc   = (unsigned short*)ws;               // 64 MiB (later: memb)
    unsigned short* hid   = (unsigned short*)(ws + 67108864);  // 64 MiB
    unsigned short* Weffb = (unsigned short*)(ws + 134217728); // 128 KiB
    float*          beff  = (float*)(ws + 134479872);          // 512 B
    unsigned short* w1b   = (unsigned short*)d_out;            // temp, dead before k_gemm2

    k_prep<<<2432, 256, 0, stream>>>(x, cw, cb, w1, w2, b2, og,
                                     enc, w1b, Weffb, beff);

    k_gemm1w<<<512, 512, 0, stream>>>(enc, w1b, b1, hid);
    k_recur<<<256, 256, 0, stream>>>((const unsigned int*)hid, (unsigned int*)enc);
    k_gemm2<<<512, 256, 0, stream>>>(Weffb, enc, beff, (float*)d_out);
}

// Round 8
// 109.884 us; speedup vs baseline: 1.1700x; 1.0702x over previous
//
#include <hip/hip_runtime.h>
#include <cstddef>
#include <cstdint>

constexpr int B_ = 64, C_ = 128, T_ = 1024, H_ = 512, ENC_ = 512;
#define ALPHA_F 0.9512294245007140f
#define ONEMA_F 0.0487705754992860f

typedef short v8s __attribute__((ext_vector_type(8)));
typedef float v4f __attribute__((ext_vector_type(4)));

#define GL16(gp, lp) __builtin_amdgcn_global_load_lds( \
    (const __attribute__((address_space(1))) unsigned int*)(gp), \
    (__attribute__((address_space(3))) unsigned int*)(lp), 16, 0, 0)

__device__ __forceinline__ unsigned short f2bf(float f) {
    union { float f; unsigned u; } v; v.f = f;
    unsigned r = v.u + 0x7FFFu + ((v.u >> 16) & 1u);
    return (unsigned short)(r >> 16);
}
__device__ __forceinline__ float bf2f(unsigned short h) {
    union { unsigned u; float f; } v; v.u = ((unsigned)h) << 16;
    return v.f;
}

// ---------------------------------------------------------------------------
// k_prep: fused {depthwise conv -> enc bf16} + {cast w1 -> bf16} + {W_eff}.
// grid: [0,2048) conv | [2048,2304) cast | [2304,2432) weff. 256 threads.
// ---------------------------------------------------------------------------
__global__ __launch_bounds__(256) void k_prep(
    const float* __restrict__ x, const float* __restrict__ cw,
    const float* __restrict__ cb, const float* __restrict__ w1,
    const float* __restrict__ w2, const float* __restrict__ b2,
    const float* __restrict__ og, unsigned short* __restrict__ enc,
    unsigned short* __restrict__ w1b, unsigned short* __restrict__ Weffb,
    float* __restrict__ beff)
{
    __shared__ float smem[132 * 33];
    const int bid = blockIdx.x;
    const int tid = threadIdx.x;

    if (bid < 2048) {
        const int b  = bid >> 5;
        const int t0 = ((bid >> 2) & 7) << 7;
        const int c0 = (bid & 3) << 5;
        const int c_l = tid & 31;
        const int tl0 = tid >> 5;
        float (*xs)[33] = (float(*)[33])smem;

        const int c = c0 + c_l;
        float wreg[20];
        {
            const float4* wp = (const float4*)(cw + (size_t)c * 20);
#pragma unroll
            for (int q = 0; q < 5; ++q) {
                const float4 v = wp[q];
                wreg[q * 4 + 0] = v.x; wreg[q * 4 + 1] = v.y;
                wreg[q * 4 + 2] = v.z; wreg[q * 4 + 3] = v.w;
            }
        }
        const float4 breg = *(const float4*)(cb + (size_t)c * 4);

        const float* xrow = x + ((size_t)b * C_ + c0) * T_;
        for (int i = tid; i < 32 * 132; i += 256) {
            const int cc = i / 132;
            const int j  = i - cc * 132;
            const int t  = t0 - 2 + j;
            float v = 0.f;
            if (t >= 0 && t < T_) v = xrow[(size_t)cc * T_ + t];
            xs[j][cc] = v;
        }
        __syncthreads();

        unsigned short* erow = enc + (size_t)(b * T_ + t0) * 512 + c * 4;
#pragma unroll
        for (int tt = 0; tt < 16; ++tt) {
            const int tl = tl0 + (tt << 3);
            const float x0 = xs[tl][c_l],     x1 = xs[tl + 1][c_l],
                        x2 = xs[tl + 2][c_l], x3 = xs[tl + 3][c_l],
                        x4 = xs[tl + 4][c_l];
            ushort4 hv;
            const float a0 = breg.x + wreg[0]*x0 + wreg[1]*x1 + wreg[2]*x2 + wreg[3]*x3 + wreg[4]*x4;
            const float a1 = breg.y + wreg[5]*x0 + wreg[6]*x1 + wreg[7]*x2 + wreg[8]*x3 + wreg[9]*x4;
            const float a2 = breg.z + wreg[10]*x0 + wreg[11]*x1 + wreg[12]*x2 + wreg[13]*x3 + wreg[14]*x4;
            const float a3 = breg.w + wreg[15]*x0 + wreg[16]*x1 + wreg[17]*x2 + wreg[18]*x3 + wreg[19]*x4;
            hv.x = f2bf(a0); hv.y = f2bf(a1); hv.z = f2bf(a2); hv.w = f2bf(a3);
            *(ushort4*)(erow + (size_t)tl * 512) = hv;
        }
    } else if (bid < 2304) {
        const int i = (bid - 2048) * 256 + tid;
        float4 v = ((const float4*)w1)[i];
        ushort4 h;
        h.x = f2bf(v.x); h.y = f2bf(v.y); h.z = f2bf(v.z); h.w = f2bf(v.w);
        ((ushort4*)w1b)[i] = h;
    } else {
        const int c = bid - 2304;
        float* ogs = smem;
        if (tid < 128) {
            float g = og[c * C_ + tid];
            if (tid == c) g = 0.f;
            ogs[tid] = g;
        }
        __syncthreads();
        if (tid < 128) {
            float acc[4];
#pragma unroll
            for (int s = 0; s < 4; ++s) acc[s] = w2[c * H_ + tid + s * 128];
            for (int cp = 0; cp < C_; ++cp) {
                const float w = ogs[cp];
#pragma unroll
                for (int s = 0; s < 4; ++s) acc[s] += w * w2[cp * H_ + tid + s * 128];
            }
#pragma unroll
            for (int s = 0; s < 4; ++s) Weffb[c * H_ + tid + s * 128] = f2bf(acc[s]);
            if (tid == 0) {
                float a = b2[c];
                for (int cp = 0; cp < C_; ++cp) a += ogs[cp] * b2[cp];
                beff[c] = a;
            }
        }
    }
}

// ---------------------------------------------------------------------------
// GEMM1, 8-phase 256x256 (T2+T3+T4+T5), BK=64, 8 waves. r5-proven (49 us).
// ---------------------------------------------------------------------------
__global__ __launch_bounds__(512, 2) void k_gemm1_8p(
    const unsigned short* __restrict__ A, const unsigned short* __restrict__ Bw,
    const float* __restrict__ bias, unsigned short* __restrict__ out)
{
    __shared__ unsigned char lds[131072];
    const int tid = threadIdx.x;
    const int lane = tid & 63;
    const int w = tid >> 6;
    const int wr = w >> 2;
    const int wc = w & 3;
    const int l15 = lane & 15;
    const int klo = lane >> 4;

    const int d = blockIdx.x;
    const int g = ((d & 7) << 6) + (d >> 3);
    const int m0 = (g >> 1) << 8;
    const int n0 = (g & 1) << 8;

    const int srow = tid >> 3;
    const int scol = ((tid & 7) ^ (srow & 7)) << 4;

    const unsigned char* Ag = (const unsigned char*)A;
    const unsigned char* Bg = (const unsigned char*)Bw;

    v4f acc[8][4];
#pragma unroll
    for (int i = 0; i < 8; ++i)
#pragma unroll
        for (int j = 0; j < 4; ++j) acc[i][j] = (v4f)0.f;

    v8s pa[2][2], pb[4][2];

#define STAGE(bufb, isB, h, ktv) do { \
    const unsigned char* sg_ = ((isB) ? Bg : Ag) + \
        (size_t)(((isB) ? n0 : m0) + (h)*128 + srow) * 1024 + (ktv)*128 + scol; \
    unsigned char* sl_ = lds + (bufb)*65536 + (isB)*32768 + (h)*16384 + tid*16; \
    GL16(sg_, sl_); \
    GL16(sg_ + 65536, sl_ + 8192); \
} while(0)

#define LDA8(bufb, q) do { \
    _Pragma("unroll") \
    for (int mi2_ = 0; mi2_ < 2; ++mi2_) { \
      _Pragma("unroll") \
      for (int ks_ = 0; ks_ < 2; ++ks_) { \
        const int row_ = wr*128 + ((q)*2 + mi2_)*16 + l15; \
        pa[mi2_][ks_] = *(const v8s*)(lds + (bufb)*65536 + row_*128 + \
            ((ks_*64 + klo*16) ^ ((row_ & 7) << 4))); \
      } } \
} while(0)

#define LDB8(bufb) do { \
    _Pragma("unroll") \
    for (int ni_ = 0; ni_ < 4; ++ni_) { \
      _Pragma("unroll") \
      for (int ks_ = 0; ks_ < 2; ++ks_) { \
        const int n_ = wc*64 + ni_*16 + l15; \
        pb[ni_][ks_] = *(const v8s*)(lds + (bufb)*65536 + 32768 + n_*128 + \
            ((ks_*64 + klo*16) ^ ((n_ & 7) << 4))); \
      } } \
} while(0)

#define MM8(q) do { \
    __builtin_amdgcn_s_setprio(1); \
    _Pragma("unroll") \
    for (int mi2_ = 0; mi2_ < 2; ++mi2_) \
      _Pragma("unroll") \
      for (int ni_ = 0; ni_ < 4; ++ni_) \
        _Pragma("unroll") \
        for (int ks_ = 0; ks_ < 2; ++ks_) \
          acc[(q)*2+mi2_][ni_] = __builtin_amdgcn_mfma_f32_16x16x32_bf16( \
              pa[mi2_][ks_], pb[ni_][ks_], acc[(q)*2+mi2_][ni_], 0, 0, 0); \
    __builtin_amdgcn_s_setprio(0); \
} while(0)

#define BAR8() do { __builtin_amdgcn_sched_barrier(0); \
    __builtin_amdgcn_s_barrier(); \
    __builtin_amdgcn_sched_barrier(0); } while(0)
#define WVM(n) do { asm volatile("s_waitcnt vmcnt(" #n ")" ::: "memory"); \
    __builtin_amdgcn_sched_barrier(0); } while(0)

    STAGE(0,1,0,0); STAGE(0,1,1,0);
    STAGE(0,0,0,0); STAGE(0,0,1,0);
    STAGE(1,1,0,1); STAGE(1,1,1,1);
    WVM(4); BAR8();

    for (int j = 0; j < 4; ++j) {
        const int sA  = 2*j + 1;
        const int sB0 = (2*j + 2) & 7;
        const int sB1 = (2*j + 3) & 7;
        LDA8(0,0); LDB8(0); STAGE(1,0,0,sA);  BAR8(); MM8(0); BAR8();
        LDA8(0,1);          STAGE(1,0,1,sA);  BAR8(); MM8(1); BAR8();
        LDA8(0,2);          STAGE(0,1,0,sB0); BAR8(); MM8(2); BAR8();
        LDA8(0,3);          STAGE(0,1,1,sB0); BAR8(); MM8(3); WVM(4); BAR8();
        LDA8(1,0); LDB8(1); STAGE(0,0,0,sB0); BAR8(); MM8(0); BAR8();
        LDA8(1,1);          STAGE(0,0,1,sB0); BAR8(); MM8(1); BAR8();
        LDA8(1,2);          STAGE(1,1,0,sB1); BAR8(); MM8(2); BAR8();
        LDA8(1,3);          STAGE(1,1,1,sB1); BAR8(); MM8(3); WVM(4); BAR8();
    }

    WVM(0); BAR8();

#pragma unroll
    for (int mi = 0; mi < 8; ++mi)
#pragma unroll
        for (int ni = 0; ni < 4; ++ni) {
            const int n = wc*64 + ni*16 + l15;
            const float bi = bias[n0 + n];
#pragma unroll
            for (int r = 0; r < 4; ++r) {
                const int m = wr*128 + mi*16 + klo*4 + r;
                *(unsigned short*)(lds + m*512 + ((2*n) ^ ((m & 7) << 4))) =
                    f2bf(acc[mi][ni][r] + bi);
            }
        }
    BAR8();
#pragma unroll
    for (int it = 0; it < 16; ++it) {
        const int idx = it*512 + tid;
        const int r = idx >> 5, s = idx & 31;
        const int4 v = *(const int4*)(lds + r*512 + ((s*16) ^ ((r & 7) << 4)));
        *(int4*)(&out[(size_t)(m0 + r)*512 + n0 + s*8]) = v;
    }
#undef STAGE
#undef LDA8
#undef LDB8
#undef MM8
#undef BAR8
#undef WVM
}

// ---------------------------------------------------------------------------
// k_rg2: FUSED LIF recurrence + GEMM2. Grid 256 = (b x 4 t-chunks of 256).
// Per block: 128-step warmup (validated alpha^128 trick), then 2 halves of:
//   R-phase: each thread owns an h-pair; scan 128 t reading hid from HBM
//            (coalesced u32, batched x16); write mem bf16x2 into swizzled
//            LDS tile mem[128t][512h] (rows 1 KB, XOR bits 4-6 by t&7).
//   G-phase: C[128c][128t] = Weffb @ mem^T; A-chunk (16 KB) staged per
//            BK=64 via global_load_lds (inverse-swizzled source, rule 21).
//   Epilogue: fp32 C staged in LDS (first 64 KB), coalesced dwordx4 stores.
// Chain state (ma,mb) persists across halves -> warmup paid once per block.
// Removes the mem HBM round-trip (recur write 64MB + gemm2 read 64MB).
// ---------------------------------------------------------------------------
__global__ __launch_bounds__(256) void k_rg2(
    const unsigned short* __restrict__ hid,
    const unsigned short* __restrict__ Weffb,
    const float* __restrict__ beff, float* __restrict__ out)
{
    __shared__ unsigned char lds[147456];   // mem tile 128 KB | A-chunk 16 KB
    unsigned char* ldsA = lds + 131072;
    const int tid = threadIdx.x;
    const int lane = tid & 63;
    const int w = tid >> 6;
    const int wm = (w & 1) << 6;   // c-offset of wave
    const int wn = (w >> 1) << 6;  // t-offset of wave
    const int l15 = lane & 15, klo = lane >> 4;

    const int b  = blockIdx.x >> 2;
    const int tc = blockIdx.x & 3;
    const int tbase = tc << 8;     // 256-live-t chunk

    // per-thread h-pair column of hid (u32 = 2 bf16)
    const unsigned int* pin = (const unsigned int*)hid + ((size_t)b << 18) + tid;

    float ma = 0.f, mb = 0.f;

    if (tc > 0) {  // warmup, read-only
        for (int t = tbase - 128; t < tbase; t += 16) {
            unsigned int v[16];
#pragma unroll
            for (int i = 0; i < 16; ++i) v[i] = pin[(size_t)(t + i) << 8];
#pragma unroll
            for (int i = 0; i < 16; ++i) {
                ma = ALPHA_F * ma + ONEMA_F * bf2f((unsigned short)(v[i] & 0xFFFFu));
                ma = (ma >= 1.0f) ? 0.f : ma;
                mb = ALPHA_F * mb + ONEMA_F * bf2f((unsigned short)(v[i] >> 16));
                mb = (mb >= 1.0f) ? 0.f : mb;
            }
        }
    }

    for (int half = 0; half < 2; ++half) {
        const int t0 = tbase + (half << 7);

        // ---- R-phase: 128 live t -> mem tile in LDS ----
        for (int t = t0; t < t0 + 128; t += 16) {
            unsigned int v[16];
#pragma unroll
            for (int i = 0; i < 16; ++i) v[i] = pin[(size_t)(t + i) << 8];
#pragma unroll
            for (int i = 0; i < 16; ++i) {
                ma = ALPHA_F * ma + ONEMA_F * bf2f((unsigned short)(v[i] & 0xFFFFu));
                ma = (ma >= 1.0f) ? 0.f : ma;
                mb = ALPHA_F * mb + ONEMA_F * bf2f((unsigned short)(v[i] >> 16));
                mb = (mb >= 1.0f) ? 0.f : mb;
                const unsigned int mv = (unsigned)f2bf(ma) | ((unsigned)f2bf(mb) << 16);
                const int tr = t + i - t0;
                *(unsigned int*)(lds + tr * 1024 + ((tid * 4) ^ ((tr & 7) << 4))) = mv;
            }
        }
        __syncthreads();  // mem tile visible to all

        // ---- G-phase: C[128c][128t] = Weffb @ mem^T ----
        v4f acc[4][4];
#pragma unroll
        for (int i = 0; i < 4; ++i)
#pragma unroll
            for (int j = 0; j < 4; ++j) acc[i][j] = (v4f)0.f;

        for (int k0 = 0; k0 < 512; k0 += 64) {
            // stage A-chunk: Weffb[128 c][k0..k0+63] -> ldsA (16 KB)
#pragma unroll
            for (int i_ = 0; i_ < 4; ++i_) {
                const int row = i_ * 32 + (tid >> 3);
                GL16((const unsigned char*)Weffb + (size_t)row * 1024 + k0 * 2 +
                         (((tid & 7) ^ (row & 7)) << 4),
                     ldsA + i_ * 4096 + tid * 16);
            }
            __syncthreads();  // vmcnt drained: A-chunk resident

#pragma unroll
            for (int ks = 0; ks < 2; ++ks) {
                v8s af[4], bfr[4];
#pragma unroll
                for (int i = 0; i < 4; ++i) {
                    const int ra = wm + i * 16 + l15;           // c row
                    const int rt = wn + i * 16 + l15;           // t row
                    const int kb = ks * 64 + klo * 16;
                    af[i]  = *(const v8s*)(ldsA + ra * 128 + (kb ^ ((ra & 7) << 4)));
                    bfr[i] = *(const v8s*)(lds + rt * 1024 +
                             ((k0 * 2 + kb) ^ ((rt & 7) << 4)));
                }
                __builtin_amdgcn_s_setprio(1);
#pragma unroll
                for (int mi = 0; mi < 4; ++mi)
#pragma unroll
                    for (int ni = 0; ni < 4; ++ni)
                        acc[mi][ni] = __builtin_amdgcn_mfma_f32_16x16x32_bf16(
                            af[mi], bfr[ni], acc[mi][ni], 0, 0, 0);
                __builtin_amdgcn_s_setprio(0);
            }
            __syncthreads();  // before next A-chunk overwrites ldsA
        }

        // ---- epilogue: stage fp32 C (64 KB) in lds[0..64K), coalesced stores
#pragma unroll
        for (int mi = 0; mi < 4; ++mi)
#pragma unroll
            for (int ni = 0; ni < 4; ++ni) {
                const int n = wn + ni * 16 + l15;   // t within 128
#pragma unroll
                for (int r = 0; r < 4; ++r) {
                    const int m = wm + mi * 16 + klo * 4 + r;  // c
                    *(float*)(lds + m * 512 + ((n * 4) ^ (((m >> 2) & 3) << 5))) =
                        acc[mi][ni][r] + beff[m];
                }
            }
        __syncthreads();
#pragma unroll
        for (int it = 0; it < 16; ++it) {
            const int idx = it * 256 + tid;
            const int r = idx >> 5, s = idx & 31;   // c row, 16B slot of t
            const int4 v = *(const int4*)(lds + r * 512 +
                ((s * 16) ^ (((r >> 2) & 3) << 5)));
            *(int4*)(&out[((size_t)(b * C_ + r) << 10) + t0 + s * 4]) = v;
        }
        __syncthreads();  // protect mem tile before next half's R-phase
    }
}

// ---------------------------------------------------------------------------
extern "C" void kernel_launch(void* const* d_in, const int* in_sizes, int n_in,
                              void* d_out, int out_size, void* d_ws, size_t ws_size,
                              hipStream_t stream)
{
    const float* x   = (const float*)d_in[0];
    const float* cw  = (const float*)d_in[1];
    const float* cb  = (const float*)d_in[2];
    const float* w1  = (const float*)d_in[3];
    const float* b1  = (const float*)d_in[4];
    const float* w2  = (const float*)d_in[5];
    const float* b2  = (const float*)d_in[6];
    const float* og  = (const float*)d_in[7];

    char* ws = (char*)d_ws;
    unsigned short* enc   = (unsigned short*)ws;               // 64 MiB
    unsigned short* hid   = (unsigned short*)(ws + 67108864);  // 64 MiB
    unsigned short* Weffb = (unsigned short*)(ws + 134217728); // 128 KiB
    float*          beff  = (float*)(ws + 134479872);          // 512 B
    unsigned short* w1b   = (unsigned short*)d_out;            // temp, dead before k_rg2

    k_prep<<<2432, 256, 0, stream>>>(x, cw, cb, w1, w2, b2, og,
                                     enc, w1b, Weffb, beff);

    k_gemm1_8p<<<512, 512, 0, stream>>>(enc, w1b, b1, hid);

    k_rg2<<<256, 256, 0, stream>>>(hid, Weffb, beff, (float*)d_out);
}

// Round 9
// 108.234 us; speedup vs baseline: 1.1878x; 1.0152x over previous
//
#include <hip/hip_runtime.h>
#include <cstddef>
#include <cstdint>

constexpr int B_ = 64, C_ = 128, T_ = 1024, H_ = 512, ENC_ = 512;
#define ALPHA_F 0.9512294245007140f
#define ONEMA_F 0.0487705754992860f

typedef short v8s __attribute__((ext_vector_type(8)));
typedef float v4f __attribute__((ext_vector_type(4)));

#define GL16(gp, lp) __builtin_amdgcn_global_load_lds( \
    (const __attribute__((address_space(1))) unsigned int*)(gp), \
    (__attribute__((address_space(3))) unsigned int*)(lp), 16, 0, 0)

__device__ __forceinline__ unsigned short f2bf(float f) {
    union { float f; unsigned u; } v; v.f = f;
    unsigned r = v.u + 0x7FFFu + ((v.u >> 16) & 1u);
    return (unsigned short)(r >> 16);
}
__device__ __forceinline__ float bf2f(unsigned short h) {
    union { unsigned u; float f; } v; v.u = ((unsigned)h) << 16;
    return v.f;
}

// ---------------------------------------------------------------------------
// k_prep: fused {depthwise conv -> enc bf16} + {cast w1 -> bf16} + {W_eff}.
// grid: [0,2048) conv | [2048,2304) cast | [2304,2432) weff. 256 threads.
// ---------------------------------------------------------------------------
__global__ __launch_bounds__(256) void k_prep(
    const float* __restrict__ x, const float* __restrict__ cw,
    const float* __restrict__ cb, const float* __restrict__ w1,
    const float* __restrict__ w2, const float* __restrict__ b2,
    const float* __restrict__ og, unsigned short* __restrict__ enc,
    unsigned short* __restrict__ w1b, unsigned short* __restrict__ Weffb,
    float* __restrict__ beff)
{
    __shared__ float smem[132 * 33];
    const int bid = blockIdx.x;
    const int tid = threadIdx.x;

    if (bid < 2048) {
        const int b  = bid >> 5;
        const int t0 = ((bid >> 2) & 7) << 7;
        const int c0 = (bid & 3) << 5;
        const int c_l = tid & 31;
        const int tl0 = tid >> 5;
        float (*xs)[33] = (float(*)[33])smem;

        const int c = c0 + c_l;
        float wreg[20];
        {
            const float4* wp = (const float4*)(cw + (size_t)c * 20);
#pragma unroll
            for (int q = 0; q < 5; ++q) {
                const float4 v = wp[q];
                wreg[q * 4 + 0] = v.x; wreg[q * 4 + 1] = v.y;
                wreg[q * 4 + 2] = v.z; wreg[q * 4 + 3] = v.w;
            }
        }
        const float4 breg = *(const float4*)(cb + (size_t)c * 4);

        const float* xrow = x + ((size_t)b * C_ + c0) * T_;
        for (int i = tid; i < 32 * 132; i += 256) {
            const int cc = i / 132;
            const int j  = i - cc * 132;
            const int t  = t0 - 2 + j;
            float v = 0.f;
            if (t >= 0 && t < T_) v = xrow[(size_t)cc * T_ + t];
            xs[j][cc] = v;
        }
        __syncthreads();

        unsigned short* erow = enc + (size_t)(b * T_ + t0) * 512 + c * 4;
#pragma unroll
        for (int tt = 0; tt < 16; ++tt) {
            const int tl = tl0 + (tt << 3);
            const float x0 = xs[tl][c_l],     x1 = xs[tl + 1][c_l],
                        x2 = xs[tl + 2][c_l], x3 = xs[tl + 3][c_l],
                        x4 = xs[tl + 4][c_l];
            ushort4 hv;
            const float a0 = breg.x + wreg[0]*x0 + wreg[1]*x1 + wreg[2]*x2 + wreg[3]*x3 + wreg[4]*x4;
            const float a1 = breg.y + wreg[5]*x0 + wreg[6]*x1 + wreg[7]*x2 + wreg[8]*x3 + wreg[9]*x4;
            const float a2 = breg.z + wreg[10]*x0 + wreg[11]*x1 + wreg[12]*x2 + wreg[13]*x3 + wreg[14]*x4;
            const float a3 = breg.w + wreg[15]*x0 + wreg[16]*x1 + wreg[17]*x2 + wreg[18]*x3 + wreg[19]*x4;
            hv.x = f2bf(a0); hv.y = f2bf(a1); hv.z = f2bf(a2); hv.w = f2bf(a3);
            *(ushort4*)(erow + (size_t)tl * 512) = hv;
        }
    } else if (bid < 2304) {
        const int i = (bid - 2048) * 256 + tid;
        float4 v = ((const float4*)w1)[i];
        ushort4 h;
        h.x = f2bf(v.x); h.y = f2bf(v.y); h.z = f2bf(v.z); h.w = f2bf(v.w);
        ((ushort4*)w1b)[i] = h;
    } else {
        const int c = bid - 2304;
        float* ogs = smem;
        if (tid < 128) {
            float g = og[c * C_ + tid];
            if (tid == c) g = 0.f;
            ogs[tid] = g;
        }
        __syncthreads();
        if (tid < 128) {
            float acc[4];
#pragma unroll
            for (int s = 0; s < 4; ++s) acc[s] = w2[c * H_ + tid + s * 128];
            for (int cp = 0; cp < C_; ++cp) {
                const float w = ogs[cp];
#pragma unroll
                for (int s = 0; s < 4; ++s) acc[s] += w * w2[cp * H_ + tid + s * 128];
            }
#pragma unroll
            for (int s = 0; s < 4; ++s) Weffb[c * H_ + tid + s * 128] = f2bf(acc[s]);
            if (tid == 0) {
                float a = b2[c];
                for (int cp = 0; cp < C_; ++cp) a += ogs[cp] * b2[cp];
                beff[c] = a;
            }
        }
    }
}

// ---------------------------------------------------------------------------
// GEMM1 v3: 256m x 128n tile, BK=32, TRIPLE-buffered 72 KB LDS -> 2 blocks/CU
// (TLP covers stalls; epilogue of one block overlaps compute of the other).
// 8 waves = 4m x 2n, per-wave 64x64 (acc 64 VGPR). Counted vmcnt(3), never 0
// mid-loop: stage kt+2 while computing kt, wait only kt+1's 3 loads.
// One barrier per K-tile. Swizzle: BK=32 rows are 64B / 4 slots of 16B;
// slot ^= (row&3) via pre-swizzled global source (rule 21); a wave's frag
// read covers 1024 contiguous LDS bytes bijectively -> conflict-free.
// Grid 1024 (bijective XCD swizzle), 2 fully-resident rounds.
// ---------------------------------------------------------------------------
__global__ __launch_bounds__(512, 4) void k_gemm1v3(
    const unsigned short* __restrict__ A, const unsigned short* __restrict__ Bw,
    const float* __restrict__ bias, unsigned short* __restrict__ out)
{
    __shared__ unsigned char lds[73728];  // buf k: [k*24576: A 16K | +16384: B 8K)
    const int tid = threadIdx.x;
    const int lane = tid & 63;
    const int w = tid >> 6;
    const int wr = w >> 1;          // 0..3 -> m-range wr*64
    const int wc = w & 1;           // 0..1 -> n-range wc*64
    const int l15 = lane & 15;
    const int klo = lane >> 4;

    const int d = blockIdx.x;                  // 1024 blocks
    const int g = ((d & 7) << 7) | (d >> 3);   // XCD-contiguous
    const int m0 = (g >> 2) << 8;
    const int n0 = (g & 3) << 7;

    const int sr = tid >> 2;                   // staging row 0..127
    const int sx = (((tid & 3) ^ (sr & 3)) << 4);  // inverse-swizzled src slot

    const unsigned char* Ag = (const unsigned char*)A;
    const unsigned char* Bg = (const unsigned char*)Bw;

    v4f acc[4][4];
#pragma unroll
    for (int i = 0; i < 4; ++i)
#pragma unroll
        for (int j = 0; j < 4; ++j) acc[i][j] = (v4f)0.f;

    v8s pa[2], pb[4];

#define STG3(sb, ktv) do { \
    GL16(Ag + (size_t)(m0 + sr) * 1024 + (ktv) * 64 + sx, \
         lds + (sb) * 24576 + tid * 16); \
    GL16(Ag + (size_t)(m0 + 128 + sr) * 1024 + (ktv) * 64 + sx, \
         lds + (sb) * 24576 + 8192 + tid * 16); \
    GL16(Bg + (size_t)(n0 + sr) * 1024 + (ktv) * 64 + sx, \
         lds + (sb) * 24576 + 16384 + tid * 16); \
} while(0)

#define LDA2(cb, q) do { \
    _Pragma("unroll") \
    for (int mi2_ = 0; mi2_ < 2; ++mi2_) { \
        const int ra_ = wr * 64 + ((q) * 2 + mi2_) * 16 + l15; \
        pa[mi2_] = *(const v8s*)(lds + (cb) * 24576 + ra_ * 64 + \
            ((klo << 4) ^ ((ra_ & 3) << 4))); \
    } \
} while(0)

#define LDB4(cb) do { \
    _Pragma("unroll") \
    for (int ni_ = 0; ni_ < 4; ++ni_) { \
        const int rb_ = wc * 64 + ni_ * 16 + l15; \
        pb[ni_] = *(const v8s*)(lds + (cb) * 24576 + 16384 + rb_ * 64 + \
            ((klo << 4) ^ ((rb_ & 3) << 4))); \
    } \
} while(0)

#define MM8(q) do { \
    __builtin_amdgcn_s_setprio(1); \
    _Pragma("unroll") \
    for (int mi2_ = 0; mi2_ < 2; ++mi2_) \
      _Pragma("unroll") \
      for (int ni_ = 0; ni_ < 4; ++ni_) \
        acc[(q) * 2 + mi2_][ni_] = __builtin_amdgcn_mfma_f32_16x16x32_bf16( \
            pa[mi2_], pb[ni_], acc[(q) * 2 + mi2_][ni_], 0, 0, 0); \
    __builtin_amdgcn_s_setprio(0); \
} while(0)

#define BARX() do { __builtin_amdgcn_sched_barrier(0); \
    __builtin_amdgcn_s_barrier(); \
    __builtin_amdgcn_sched_barrier(0); } while(0)

    // prologue: stage kt0 -> buf0, kt1 -> buf1; wait kt0 (leave kt1 in flight)
    STG3(0, 0);
    STG3(1, 1);
    asm volatile("s_waitcnt vmcnt(3)" ::: "memory");
    BARX();

    for (int kt = 0; kt < 16; ++kt) {
        const int cb = kt % 3;
        const int sb = (kt + 2) % 3;
        LDB4(cb);
        LDA2(cb, 0);
        if (kt <= 13) STG3(sb, kt + 2);
        MM8(0);
        LDA2(cb, 1);
        MM8(1);
        if (kt <= 13) {
            asm volatile("s_waitcnt vmcnt(3)" ::: "memory");
        } else {
            asm volatile("s_waitcnt vmcnt(0)" ::: "memory");
        }
        BARX();
    }

    // epilogue: C 256x128 bf16 (64 KB) via LDS, coalesced 256B stores
#pragma unroll
    for (int mi = 0; mi < 4; ++mi)
#pragma unroll
        for (int ni = 0; ni < 4; ++ni) {
            const int n = wc * 64 + ni * 16 + l15;
            const float bi = bias[n0 + n];
#pragma unroll
            for (int r = 0; r < 4; ++r) {
                const int m = wr * 64 + mi * 16 + klo * 4 + r;
                *(unsigned short*)(lds + m * 256 +
                    ((2 * n) ^ (((m >> 2) & 3) << 5))) =
                    f2bf(acc[mi][ni][r] + bi);
            }
        }
    BARX();
#pragma unroll
    for (int it = 0; it < 8; ++it) {
        const int idx = it * 512 + tid;       // 0..4095
        const int r = idx >> 4, s = idx & 15;
        const int4 v = *(const int4*)(lds + r * 256 +
            ((s * 16) ^ (((r >> 2) & 3) << 5)));
        *(int4*)(&out[(size_t)(m0 + r) * 512 + n0 + s * 8]) = v;
    }
#undef STG3
#undef LDA2
#undef LDB4
#undef MM8
#undef BARX
}

// ---------------------------------------------------------------------------
// k_rg2: FUSED LIF recurrence + GEMM2 (r8-proven). Grid 256 = (b x 4 chunks).
// ---------------------------------------------------------------------------
__global__ __launch_bounds__(256) void k_rg2(
    const unsigned short* __restrict__ hid,
    const unsigned short* __restrict__ Weffb,
    const float* __restrict__ beff, float* __restrict__ out)
{
    __shared__ unsigned char lds[147456];   // mem tile 128 KB | A-chunk 16 KB
    unsigned char* ldsA = lds + 131072;
    const int tid = threadIdx.x;
    const int lane = tid & 63;
    const int w = tid >> 6;
    const int wm = (w & 1) << 6;
    const int wn = (w >> 1) << 6;
    const int l15 = lane & 15, klo = lane >> 4;

    const int b  = blockIdx.x >> 2;
    const int tc = blockIdx.x & 3;
    const int tbase = tc << 8;

    const unsigned int* pin = (const unsigned int*)hid + ((size_t)b << 18) + tid;

    float ma = 0.f, mb = 0.f;

    if (tc > 0) {
        for (int t = tbase - 128; t < tbase; t += 16) {
            unsigned int v[16];
#pragma unroll
            for (int i = 0; i < 16; ++i) v[i] = pin[(size_t)(t + i) << 8];
#pragma unroll
            for (int i = 0; i < 16; ++i) {
                ma = ALPHA_F * ma + ONEMA_F * bf2f((unsigned short)(v[i] & 0xFFFFu));
                ma = (ma >= 1.0f) ? 0.f : ma;
                mb = ALPHA_F * mb + ONEMA_F * bf2f((unsigned short)(v[i] >> 16));
                mb = (mb >= 1.0f) ? 0.f : mb;
            }
        }
    }

    for (int half = 0; half < 2; ++half) {
        const int t0 = tbase + (half << 7);

        for (int t = t0; t < t0 + 128; t += 16) {
            unsigned int v[16];
#pragma unroll
            for (int i = 0; i < 16; ++i) v[i] = pin[(size_t)(t + i) << 8];
#pragma unroll
            for (int i = 0; i < 16; ++i) {
                ma = ALPHA_F * ma + ONEMA_F * bf2f((unsigned short)(v[i] & 0xFFFFu));
                ma = (ma >= 1.0f) ? 0.f : ma;
                mb = ALPHA_F * mb + ONEMA_F * bf2f((unsigned short)(v[i] >> 16));
                mb = (mb >= 1.0f) ? 0.f : mb;
                const unsigned int mv = (unsigned)f2bf(ma) | ((unsigned)f2bf(mb) << 16);
                const int tr = t + i - t0;
                *(unsigned int*)(lds + tr * 1024 + ((tid * 4) ^ ((tr & 7) << 4))) = mv;
            }
        }
        __syncthreads();

        v4f acc[4][4];
#pragma unroll
        for (int i = 0; i < 4; ++i)
#pragma unroll
            for (int j = 0; j < 4; ++j) acc[i][j] = (v4f)0.f;

        for (int k0 = 0; k0 < 512; k0 += 64) {
#pragma unroll
            for (int i_ = 0; i_ < 4; ++i_) {
                const int row = i_ * 32 + (tid >> 3);
                GL16((const unsigned char*)Weffb + (size_t)row * 1024 + k0 * 2 +
                         (((tid & 7) ^ (row & 7)) << 4),
                     ldsA + i_ * 4096 + tid * 16);
            }
            __syncthreads();

#pragma unroll
            for (int ks = 0; ks < 2; ++ks) {
                v8s af[4], bfr[4];
#pragma unroll
                for (int i = 0; i < 4; ++i) {
                    const int ra = wm + i * 16 + l15;
                    const int rt = wn + i * 16 + l15;
                    const int kb = ks * 64 + klo * 16;
                    af[i]  = *(const v8s*)(ldsA + ra * 128 + (kb ^ ((ra & 7) << 4)));
                    bfr[i] = *(const v8s*)(lds + rt * 1024 +
                             ((k0 * 2 + kb) ^ ((rt & 7) << 4)));
                }
                __builtin_amdgcn_s_setprio(1);
#pragma unroll
                for (int mi = 0; mi < 4; ++mi)
#pragma unroll
                    for (int ni = 0; ni < 4; ++ni)
                        acc[mi][ni] = __builtin_amdgcn_mfma_f32_16x16x32_bf16(
                            af[mi], bfr[ni], acc[mi][ni], 0, 0, 0);
                __builtin_amdgcn_s_setprio(0);
            }
            __syncthreads();
        }

#pragma unroll
        for (int mi = 0; mi < 4; ++mi)
#pragma unroll
            for (int ni = 0; ni < 4; ++ni) {
                const int n = wn + ni * 16 + l15;
#pragma unroll
                for (int r = 0; r < 4; ++r) {
                    const int m = wm + mi * 16 + klo * 4 + r;
                    *(float*)(lds + m * 512 + ((n * 4) ^ (((m >> 2) & 3) << 5))) =
                        acc[mi][ni][r] + beff[m];
                }
            }
        __syncthreads();
#pragma unroll
        for (int it = 0; it < 16; ++it) {
            const int idx = it * 256 + tid;
            const int r = idx >> 5, s = idx & 31;
            const int4 v = *(const int4*)(lds + r * 512 +
                ((s * 16) ^ (((r >> 2) & 3) << 5)));
            *(int4*)(&out[((size_t)(b * C_ + r) << 10) + t0 + s * 4]) = v;
        }
        __syncthreads();
    }
}

// ---------------------------------------------------------------------------
extern "C" void kernel_launch(void* const* d_in, const int* in_sizes, int n_in,
                              void* d_out, int out_size, void* d_ws, size_t ws_size,
                              hipStream_t stream)
{
    const float* x   = (const float*)d_in[0];
    const float* cw  = (const float*)d_in[1];
    const float* cb  = (const float*)d_in[2];
    const float* w1  = (const float*)d_in[3];
    const float* b1  = (const float*)d_in[4];
    const float* w2  = (const float*)d_in[5];
    const float* b2  = (const float*)d_in[6];
    const float* og  = (const float*)d_in[7];

    char* ws = (char*)d_ws;
    unsigned short* enc   = (unsigned short*)ws;               // 64 MiB
    unsigned short* hid   = (unsigned short*)(ws + 67108864);  // 64 MiB
    unsigned short* Weffb = (unsigned short*)(ws + 134217728); // 128 KiB
    float*          beff  = (float*)(ws + 134479872);          // 512 B
    unsigned short* w1b   = (unsigned short*)d_out;            // temp, dead before k_rg2

    k_prep<<<2432, 256, 0, stream>>>(x, cw, cb, w1, w2, b2, og,
                                     enc, w1b, Weffb, beff);

    k_gemm1v3<<<1024, 512, 0, stream>>>(enc, w1b, b1, hid);

    k_rg2<<<256, 256, 0, stream>>>(hid, Weffb, beff, (float*)d_out);
}